// Round 2
// baseline (394.562 us; speedup 1.0000x reference)
//
#include <hip/hip_runtime.h>
#include <hip/hip_fp16.h>

// Problem constants
#define C_   64
#define H_   256
#define W_   256
#define L0_  1024
#define L1_  1024
#define JT   64     // j-tile (g0/output-inner dim) per block
#define HSTR 261    // halfs per hy row: 259 slots (x-ext -1..257) + pad; odd word stride -> bank spread

// out[c][i][j] = sum_a wx[i,a] * sum_b wy[j,b] * v[c][ yi[j,b] ][ xi[i,a] ]
//   i indexes L1 (g1 -> x taps over W), j indexes L0 (g0 -> y taps over H).
// Strategy: y-interp first (row gathers are coalesced), x-interp second from LDS.

__device__ __forceinline__ void cubic_weights(float t, float w[4]) {
    const float A = -0.75f;
    float t2 = t * t, t3 = t2 * t;
    w[0] = A * (t3 - 2.f * t2 + t);
    w[1] = (A + 2.f) * t3 - (A + 3.f) * t2 + 1.f;
    float s = 1.f - t, s2 = s * s;
    w[2] = (A + 2.f) * s2 * s - (A + 3.f) * s2 + 1.f;
    float u = 2.f - t, u2 = u * u;
    w[3] = A * u2 * u - 5.f * A * u2 + 8.f * A * u - 4.f * A;
}

__global__ __launch_bounds__(256, 3) void bicubic_sep(const float* __restrict__ v,
                                                      const float* __restrict__ g0,
                                                      const float* __restrict__ g1,
                                                      float* __restrict__ out) {
    __shared__ __half hy[JT * HSTR];   // 33,408 B: y-interpolated rows, fp16, x-halo'd
    __shared__ float4 wx4[L1_];        // 16,384 B: x-tap weights per i
    __shared__ int    xbs[L1_];        //  4,096 B: x-tap base per i (floor(x), in [0,255])
                                       // total 53,888 B -> 3 blocks/CU

    const int c  = blockIdx.x;         // c on x-dim: all j-tiles of a channel hit same XCD
    const int j0 = blockIdx.y * JT;
    const int t  = threadIdx.x;        // 256 threads

    // Phase 0: x-tap table for all 1024 i (tiny; recomputed per block)
    for (int i = t; i < L1_; i += 256) {
        float x  = (g1[i] + 1.f) * 0.5f * (float)(W_ - 1);
        float x0 = floorf(x);
        float w[4];
        cubic_weights(x - x0, w);
        wx4[i] = make_float4(w[0], w[1], w[2], w[3]);
        xbs[i] = (int)x0;              // halo layout absorbs the -1..+2 clamp
    }

    // Phase 1: y-interpolate all 256 columns for the 64 j's. lane = x -> coalesced rows.
    {
        const float* vc = v + (size_t)c * (H_ * W_);
#pragma unroll 2
        for (int j = 0; j < JT; ++j) {
            float yf = (g0[j0 + j] + 1.f) * 0.5f * (float)(H_ - 1);
            float y0 = floorf(yf);
            float wy[4];
            cubic_weights(yf - y0, wy);
            int yb  = (int)y0;
            int y0i = min(max(yb - 1, 0), H_ - 1);
            int y1i = min(max(yb,     0), H_ - 1);
            int y2i = min(max(yb + 1, 0), H_ - 1);
            int y3i = min(max(yb + 2, 0), H_ - 1);
            float acc = wy[0] * vc[y0i * W_ + t] + wy[1] * vc[y1i * W_ + t]
                      + wy[2] * vc[y2i * W_ + t] + wy[3] * vc[y3i * W_ + t];
            __half h = __float2half(acc);
            hy[j * HSTR + 1 + t] = h;            // ext slot s = x+1 (s-1 = x)
            if (t == 0) {
                hy[j * HSTR + 0] = h;            // ext x = -1  -> clamp to 0
            } else if (t == W_ - 1) {
                hy[j * HSTR + 257] = h;          // ext x = 256 -> clamp to 255
                hy[j * HSTR + 258] = h;          // ext x = 257 -> clamp to 255
            }
        }
    }
    __syncthreads();

    // Phase 2: x-interp. Wave w owns i = w, w+4, ...; lane jt = j. Stores: 64 contiguous floats.
    const int w  = t >> 6;
    const int jt = t & 63;
    const __half* hrow = hy + jt * HSTR;
    float* orow = out + (size_t)c * L1_ * L0_ + j0 + jt;

#pragma unroll 4
    for (int i = w; i < L1_; i += 4) {
        float4 wx = wx4[i];            // wave-uniform -> LDS broadcast
        int    xb = xbs[i];
        const __half* p = hrow + xb;   // ext slots xb..xb+3 == taps clamp(xb-1..xb+2)
        float o = wx.x * __half2float(p[0]) + wx.y * __half2float(p[1])
                + wx.z * __half2float(p[2]) + wx.w * __half2float(p[3]);
        orow[(size_t)i * L0_] = o;
    }
}

extern "C" void kernel_launch(void* const* d_in, const int* in_sizes, int n_in,
                              void* d_out, int out_size, void* d_ws, size_t ws_size,
                              hipStream_t stream) {
    const float* values = (const float*)d_in[0];  // (1, C, H, W) fp32
    const float* g0     = (const float*)d_in[1];  // (L0,) -> y axis / output inner dim
    const float* g1     = (const float*)d_in[2];  // (L1,) -> x axis / output outer dim
    float* out          = (float*)d_out;          // (1, C, L1, L0) fp32

    dim3 grid(C_, L0_ / JT);   // (64, 16) = 1024 blocks
    bicubic_sep<<<grid, 256, 0, stream>>>(values, g0, g1, out);
}